// Round 11
// baseline (108.366 us; speedup 1.0000x reference)
//
#include <hip/hip_runtime.h>
#include <hip/hip_bf16.h>
#include <math.h>

#define EMB 256
#define HEADS 4
#define HD 64
#define NTOK 4096

typedef __attribute__((ext_vector_type(8))) short bf16x8;
typedef __attribute__((ext_vector_type(4))) float f32x4;
typedef __attribute__((ext_vector_type(16))) float f32x16;
typedef __attribute__((ext_vector_type(2))) unsigned int uint2v;

#define MFMA16(a, b, c) __builtin_amdgcn_mfma_f32_16x16x32_bf16(a, b, c, 0, 0, 0)
#define MFMA32(a, b, c) __builtin_amdgcn_mfma_f32_32x32x16_bf16(a, b, c, 0, 0, 0)

static __device__ __forceinline__ ushort f2bf(float f) {
    __hip_bfloat16 h = __float2bfloat16(f);
    return *(ushort*)&h;
}
static __device__ __forceinline__ float ex2(float x) { return __builtin_amdgcn_exp2f(x); }
static __device__ __forceinline__ uint pkbf(float lo, float hi) {
    uint r;
    asm("v_cvt_pk_bf16_f32 %0, %1, %2" : "=v"(r) : "v"(lo), "v"(hi));
    return r;
}
static __device__ __forceinline__ float max3f(float a, float b, float c) {
    float r;
    asm("v_max3_f32 %0, %1, %2, %3" : "=v"(r) : "v"(a), "v"(b), "v"(c));
    return r;
}
// cross-half (lane^32) reductions on the VALU pipe via self permlane32_swap
static __device__ __forceinline__ float redmax32(float x) {
    uint xi = __float_as_uint(x);
    uint2v r = __builtin_amdgcn_permlane32_swap(xi, xi, false, false);
    return fmaxf(__uint_as_float(r[0]), __uint_as_float(r[1]));
}
static __device__ __forceinline__ float redsum32(float x) {
    uint xi = __float_as_uint(x);
    uint2v r = __builtin_amdgcn_permlane32_swap(xi, xi, false, false);
    return __uint_as_float(r[0]) + __uint_as_float(r[1]);
}
static __device__ __forceinline__ bf16x8 cvt8(float4 a, float4 b) {
    union { uint u[4]; bf16x8 h; } pk;
    pk.u[0] = pkbf(a.x, a.y);
    pk.u[1] = pkbf(a.z, a.w);
    pk.u[2] = pkbf(b.x, b.y);
    pk.u[3] = pkbf(b.z, b.w);
    return pk.h;
}
static __device__ __forceinline__ float bf2f(ushort u) {
    return __uint_as_float(((uint)u) << 16);
}

// ---------------- A,B f32 -> bf16 ----------------
__global__ void cvtAB(const float* __restrict__ A, const float* __restrict__ B,
                      ushort* __restrict__ Ao, ushort* __restrict__ Bo) {
    const float* s = blockIdx.y ? B : A;
    ushort* d = blockIdx.y ? Bo : Ao;
    int i = (blockIdx.x * 256 + threadIdx.x) * 4;
    float4 v = *(const float4*)(s + i);
    ushort4 o;
    o.x = f2bf(v.x); o.y = f2bf(v.y); o.z = f2bf(v.z); o.w = f2bf(v.w);
    *(ushort4*)(d + i) = o;
}

// ---------------- weights f32 -> bf16 ----------------
__global__ void cvtW(const float* __restrict__ Wq, const float* __restrict__ Wk,
                     const float* __restrict__ Wv, const float* __restrict__ Wo,
                     ushort* __restrict__ Wall) {
    const float* s = (blockIdx.y == 0) ? Wq : (blockIdx.y == 1) ? Wk : (blockIdx.y == 2) ? Wv : Wo;
    ushort* d = Wall + (size_t)blockIdx.y * 65536;
    int i = (blockIdx.x * 256 + threadIdx.x) * 4;
    float4 v = *(const float4*)(s + i);
    ushort4 o;
    o.x = f2bf(v.x); o.y = f2bf(v.y); o.z = f2bf(v.z); o.w = f2bf(v.w);
    *(ushort4*)(d + i) = o;
}

// ---------------- QKV projection (separate kinds; bf16 X input) ----------------
// kind=0: Q [m][256] pre-scaled by log2(e)/8; kind=1: K [m][256]
// kind=2: V transposed per head, token bit-2/3-swapped: Vt[h][d][perm(m)]
// NOTE: keep kinds SEPARATE — fusing the 3 projections in one block blows
// absmax 0.0156->0.082 (R6-R9 controlled experiment).
__global__ __launch_bounds__(256) void qkv_proj(const ushort* __restrict__ Xa,
                                                const ushort* __restrict__ Xb,
                                                const ushort* __restrict__ Wall,
                                                ushort* __restrict__ Q0, ushort* __restrict__ K1, ushort* __restrict__ Vt1,
                                                ushort* __restrict__ Q1, ushort* __restrict__ K0, ushort* __restrict__ Vt0) {
    int w = threadIdx.x >> 6, lane = threadIdx.x & 63;
    int lr = lane & 15, lg = lane >> 4;
    int z = blockIdx.z;
    int kind = (z < 3) ? z : z - 3;
    const ushort* X = (z < 3) ? Xa : Xb;
    ushort* Qo = (z < 3) ? Q0 : Q1;
    ushort* Ko = (z < 3) ? K1 : K0;
    ushort* Vto = (z < 3) ? Vt1 : Vt0;
    const ushort* W = Wall + (size_t)kind * 65536;
    int rbase = blockIdx.x * 64 + w * 16;
    int cbase = blockIdx.y * 64;

    f32x4 acc[4] = {};
#pragma unroll
    for (int kk = 0; kk < 256; kk += 32) {
        bf16x8 a = *(const bf16x8*)(X + (size_t)(rbase + lr) * EMB + kk + lg * 8);
#pragma unroll
        for (int cj = 0; cj < 4; ++cj) {
            bf16x8 b = *(const bf16x8*)(W + (size_t)(cbase + cj * 16 + lr) * EMB + kk + lg * 8);
            acc[cj] = MFMA16(a, b, acc[cj]);
        }
    }
    const float QS = 0.125f * 1.4426950408889634f;  // 1/sqrt(64) * log2(e)
#pragma unroll
    for (int cj = 0; cj < 4; ++cj)
#pragma unroll
        for (int j = 0; j < 4; ++j) {
            int R = rbase + lg * 4 + j;
            int col = cbase + cj * 16 + lr;
            float v = acc[cj][j];
            if (kind == 0) {
                Qo[(size_t)R * EMB + col] = f2bf(v * QS);
            } else if (kind == 1) {
                Ko[(size_t)R * EMB + col] = f2bf(v);
            } else {
                int h = col >> 6, d = col & 63;
                int Rp = (R & ~12) | ((R & 4) << 1) | ((R & 8) >> 1);  // swap bits 2,3
                Vto[(size_t)h * HD * NTOK + (size_t)d * NTOK + Rp] = f2bf(v);
            }
        }
}

// ---------------- flash cross-attention, swapped-QK 32x32, kv-split=4 ----------------
// grid (32,4,8): 1024 blocks. Double-buffered LDS, ONE barrier/tile.
// Occupancy is capped by the unified reg file (~128/wave incl AGPR acc) at 4
// waves/SIMD — do NOT trade LDS for occupancy (R9), do NOT force (256,8) (R6).
__global__ __launch_bounds__(256, 4) void attn(const ushort* __restrict__ Q0,
                                               const ushort* __restrict__ K0,
                                               const ushort* __restrict__ Vt0,
                                               const ushort* __restrict__ Q1,
                                               const ushort* __restrict__ K1,
                                               const ushort* __restrict__ Vt1,
                                               ushort* __restrict__ Opart,
                                               float* __restrict__ ML) {
    __shared__ ushort lK[2][64 * 64];
    __shared__ ushort lV[2][64 * 64];

    // bijective XCD swizzle over 1024 blocks
    int fb = blockIdx.x + 32 * blockIdx.y + 128 * blockIdx.z;
    int nf = (fb & 7) * 128 + (fb >> 3);
    int qt = nf & 31;
    int head = (nf >> 5) & 3;
    int z = nf >> 7;               // 0..7
    int dir = z >> 2, split = z & 3;
    int kv0 = split * 1024;

    const ushort* Q = dir ? Q1 : Q0;
    const ushort* K = dir ? K1 : K0;
    const ushort* Vt = dir ? Vt1 : Vt0;
    const ushort* Vth = Vt + (size_t)head * HD * NTOK;

    int wq = threadIdx.x >> 6;
    int lane = threadIdx.x & 63;
    int l31 = lane & 31, hi = lane >> 5;

    int qg = qt * 128 + wq * 32 + l31;
    bf16x8 qf[4];
#pragma unroll
    for (int ks = 0; ks < 4; ++ks)
        qf[ks] = *(const bf16x8*)(Q + (size_t)qg * EMB + head * 64 + ks * 16 + hi * 8);

    int srow = threadIdx.x >> 3, sseg = threadIdx.x & 7;
    int ssw = (sseg ^ ((srow >> 2) & 7)) * 8;  // f(r)=(r>>2)&7; f(r+32)==f(r)

    // prologue: prefetch tile 0
    uint4 rk0 = *(const uint4*)(K + (size_t)(kv0 + srow) * EMB + head * 64 + sseg * 8);
    uint4 rk1 = *(const uint4*)(K + (size_t)(kv0 + srow + 32) * EMB + head * 64 + sseg * 8);
    uint4 rv0 = *(const uint4*)(Vth + (size_t)srow * NTOK + kv0 + sseg * 8);
    uint4 rv1 = *(const uint4*)(Vth + (size_t)(srow + 32) * NTOK + kv0 + sseg * 8);

    float m = -1e30f, ls = 0.0f;
    f32x16 oacc0 = {};
    f32x16 oacc1 = {};
    int sw = (l31 >> 2) & 7;  // read-side swizzle key (rows l31 and 32+l31 share it)

    for (int t = 0; t < 16; ++t) {
        int cur = t & 1;
        ushort* lk = &lK[cur][0];
        ushort* lv = &lV[cur][0];
        *(uint4*)(&lk[srow * 64 + ssw]) = rk0;
        *(uint4*)(&lk[(srow + 32) * 64 + ssw]) = rk1;
        *(uint4*)(&lv[srow * 64 + ssw]) = rv0;
        *(uint4*)(&lv[(srow + 32) * 64 + ssw]) = rv1;
        __syncthreads();  // sole barrier: buffer ready for all

        if (t < 15) {
            int nkv = kv0 + (t + 1) * 64;
            rk0 = *(const uint4*)(K + (size_t)(nkv + srow) * EMB + head * 64 + sseg * 8);
            rk1 = *(const uint4*)(K + (size_t)(nkv + srow + 32) * EMB + head * 64 + sseg * 8);
            rv0 = *(const uint4*)(Vth + (size_t)srow * NTOK + nkv + sseg * 8);
            rv1 = *(const uint4*)(Vth + (size_t)(srow + 32) * NTOK + nkv + sseg * 8);
        }

        // QK^T swapped: lane holds 32 scores for q-row l31
        f32x16 sA = {}, sB = {};
        __builtin_amdgcn_s_setprio(1);
#pragma unroll
        for (int ks = 0; ks < 4; ++ks) {
            bf16x8 ka = *(const bf16x8*)(&lk[l31 * 64 + ((ks * 2 + hi) ^ sw) * 8]);
            bf16x8 kb = *(const bf16x8*)(&lk[(32 + l31) * 64 + ((ks * 2 + hi) ^ sw) * 8]);
            sA = MFMA32(ka, qf[ks], sA);
            sB = MFMA32(kb, qf[ks], sB);
        }
        __builtin_amdgcn_s_setprio(0);

        // tile max via v_max3 tree
        float t0 = max3f(sA[0], sA[1], sA[2]);
        float t1 = max3f(sA[3], sA[4], sA[5]);
        float t2 = max3f(sA[6], sA[7], sA[8]);
        float t3 = max3f(sA[9], sA[10], sA[11]);
        float t4 = max3f(sA[12], sA[13], sA[14]);
        float t5 = max3f(sB[0], sB[1], sB[2]);
        float t6 = max3f(sB[3], sB[4], sB[5]);
        float t7 = max3f(sB[6], sB[7], sB[8]);
        float t8 = max3f(sB[9], sB[10], sB[11]);
        float t9 = max3f(sB[12], sB[13], sB[14]);
        float ta = fmaxf(sA[15], sB[15]);
        float u0 = max3f(t0, t1, t2);
        float u1 = max3f(t3, t4, t5);
        float u2 = max3f(t6, t7, t8);
        float u3 = fmaxf(t9, ta);
        float tmax = redmax32(fmaxf(max3f(u0, u1, u2), u3));

        // defer-max (THR=8)
        if (__any(tmax > m + 8.0f)) {
            float mn = fmaxf(m, tmax);
            float sc = ex2(m - mn);
            m = mn;
            ls *= sc;
#pragma unroll
            for (int r = 0; r < 16; ++r) { oacc0[r] *= sc; oacc1[r] *= sc; }
        }

#pragma unroll
        for (int r = 0; r < 16; ++r) sA[r] = ex2(sA[r] - m);
#pragma unroll
        for (int r = 0; r < 16; ++r) sB[r] = ex2(sB[r] - m);

        // pairwise-tree row sum
        float s1[16];
#pragma unroll
        for (int i = 0; i < 8; ++i) s1[i] = sA[2 * i] + sA[2 * i + 1];
#pragma unroll
        for (int i = 0; i < 8; ++i) s1[8 + i] = sB[2 * i] + sB[2 * i + 1];
#pragma unroll
        for (int w2 = 8; w2 >= 1; w2 >>= 1)
#pragma unroll
            for (int i = 0; i < 8; ++i)
                if (i < w2) s1[i] = s1[2 * i] + s1[2 * i + 1];
        ls += redsum32(s1[0]);

        // P -> bf16 fragments (lane-local; V pre-permuted to match)
        bf16x8 pa[4];
#pragma unroll
        for (int ks = 0; ks < 4; ++ks) {
            union { uint u[4]; bf16x8 h; } pk;
#pragma unroll
            for (int j = 0; j < 4; ++j) {
                float lo = (ks < 2) ? sA[(ks & 1) * 8 + 2 * j] : sB[(ks & 1) * 8 + 2 * j];
                float hv = (ks < 2) ? sA[(ks & 1) * 8 + 2 * j + 1] : sB[(ks & 1) * 8 + 2 * j + 1];
                pk.u[j] = pkbf(lo, hv);
            }
            pa[ks] = pk.h;
        }

        __builtin_amdgcn_s_setprio(1);
#pragma unroll
        for (int ks = 0; ks < 4; ++ks) {
            bf16x8 va = *(const bf16x8*)(&lv[l31 * 64 + ((ks * 2 + hi) ^ sw) * 8]);
            bf16x8 vb = *(const bf16x8*)(&lv[(32 + l31) * 64 + ((ks * 2 + hi) ^ sw) * 8]);
            oacc0 = MFMA32(va, pa[ks], oacc0);
            oacc1 = MFMA32(vb, pa[ks], oacc1);
        }
        __builtin_amdgcn_s_setprio(0);
    }

    // epilogue: unnormalized bf16 partials, vectorized 8B stores.
    // crow = (r&3) + 8*(r>>2) + 4*hi: for r=4g+j, crow = 8g + 4hi + j (j=0..3).
    ushort* Ob = Opart + ((size_t)z * 4096 + qg) * 256 + head * 64;
#pragma unroll
    for (int g = 0; g < 4; ++g) {
        uint2 o0, o1;
        o0.x = pkbf(oacc0[4 * g + 0], oacc0[4 * g + 1]);
        o0.y = pkbf(oacc0[4 * g + 2], oacc0[4 * g + 3]);
        o1.x = pkbf(oacc1[4 * g + 0], oacc1[4 * g + 1]);
        o1.y = pkbf(oacc1[4 * g + 2], oacc1[4 * g + 3]);
        *(uint2*)(&Ob[8 * g + 4 * hi]) = o0;
        *(uint2*)(&Ob[32 + 8 * g + 4 * hi]) = o1;
    }
    if (hi == 0) {
        float2* mlp = (float2*)ML;
        mlp[((size_t)z * 4 + head) * 4096 + qg] = make_float2(m, ls);
    }
}

// ---------------- fused 4-way merge + output projection (R9-proven) ----------------
__global__ __launch_bounds__(256) void out_proj(const ushort* __restrict__ Opart,
                                                const float* __restrict__ ML,
                                                const ushort* __restrict__ Wo,
                                                const float* __restrict__ bo,
                                                const float* __restrict__ A,
                                                const float* __restrict__ B,
                                                float* __restrict__ out) {
    int dir = blockIdx.z;
    const float* X = dir ? B : A;
    float* o = out + (size_t)dir * NTOK * EMB;

    int w = threadIdx.x >> 6, lane = threadIdx.x & 63;
    int lr = lane & 15, lg = lane >> 4;
    int rbase = blockIdx.x * 64 + w * 16;
    int cbase = blockIdx.y * 64;
    int R = rbase + lr;  // A-fragment row for this lane

    // per-head normalized merge weights over the 4 kv-splits
    const float2* mlp = (const float2*)ML;
    float Wm[4][4];
#pragma unroll
    for (int h = 0; h < 4; ++h) {
        float2 ml[4];
        float M = -1e30f;
#pragma unroll
        for (int s = 0; s < 4; ++s) {
            ml[s] = mlp[((size_t)(dir * 4 + s) * 4 + h) * 4096 + R];
            M = fmaxf(M, ml[s].x);
        }
        float denom = 0.0f, a[4];
#pragma unroll
        for (int s = 0; s < 4; ++s) { a[s] = ex2(ml[s].x - M); denom += a[s] * ml[s].y; }
        float inv = 1.0f / denom;
#pragma unroll
        for (int s = 0; s < 4; ++s) Wm[h][s] = a[s] * inv;
    }

    const ushort* Or[4];
#pragma unroll
    for (int s = 0; s < 4; ++s)
        Or[s] = Opart + ((size_t)(dir * 4 + s) * 4096 + R) * 256;

    f32x4 acc[4] = {};
#pragma unroll
    for (int kk = 0; kk < 256; kk += 32) {
        int h = kk >> 6;
        bf16x8 xs0 = *(const bf16x8*)(Or[0] + kk + lg * 8);
        bf16x8 xs1 = *(const bf16x8*)(Or[1] + kk + lg * 8);
        bf16x8 xs2 = *(const bf16x8*)(Or[2] + kk + lg * 8);
        bf16x8 xs3 = *(const bf16x8*)(Or[3] + kk + lg * 8);
        float cv[8];
#pragma unroll
        for (int u = 0; u < 8; ++u) {
            cv[u] = Wm[h][0] * bf2f((ushort)xs0[u]) + Wm[h][1] * bf2f((ushort)xs1[u])
                  + Wm[h][2] * bf2f((ushort)xs2[u]) + Wm[h][3] * bf2f((ushort)xs3[u]);
        }
        float4 c0 = {cv[0], cv[1], cv[2], cv[3]};
        float4 c1 = {cv[4], cv[5], cv[6], cv[7]};
        bf16x8 a = cvt8(c0, c1);
#pragma unroll
        for (int cj = 0; cj < 4; ++cj) {
            bf16x8 b = *(const bf16x8*)(Wo + (size_t)(cbase + cj * 16 + lr) * EMB + kk + lg * 8);
            acc[cj] = MFMA16(a, b, acc[cj]);
        }
    }
#pragma unroll
    for (int cj = 0; cj < 4; ++cj)
#pragma unroll
        for (int j = 0; j < 4; ++j) {
            int Rr = rbase + lg * 4 + j;
            int col = cbase + cj * 16 + lr;
            o[(size_t)Rr * EMB + col] = acc[cj][j] + bo[col] + X[(size_t)Rr * EMB + col];
        }
}

extern "C" void kernel_launch(void* const* d_in, const int* in_sizes, int n_in,
                              void* d_out, int out_size, void* d_ws, size_t ws_size,
                              hipStream_t stream) {
    const float* A  = (const float*)d_in[0];
    const float* B  = (const float*)d_in[1];
    const float* Wq = (const float*)d_in[2];
    const float* Wk = (const float*)d_in[3];
    const float* Wv = (const float*)d_in[4];
    const float* Wo = (const float*)d_in[5];
    const float* bo = (const float*)d_in[6];
    float* out = (float*)d_out;

    ushort* ws = (ushort*)d_ws;
    const size_t TE = (size_t)NTOK * EMB;  // 1048576 elements
    ushort* wall = ws;                 // 4 * 65536
    ushort* abf = wall + 4 * 65536;
    ushort* bbf = abf + TE;
    ushort* q0  = bbf + TE;
    ushort* q1  = q0 + TE;
    ushort* k0  = q1 + TE;
    ushort* k1  = k0 + TE;
    ushort* vt0 = k1 + TE;
    ushort* vt1 = vt0 + TE;
    ushort* Opart = vt1 + TE;                              // 8 x 4096 x 256 bf16 = 16 MB
    float* ML = (float*)(Opart + (size_t)8 * 4096 * 256);  // 8 x 4 x 4096 float2 = 1 MB

    cvtAB<<<dim3(1024, 2), 256, 0, stream>>>(A, B, abf, bbf);
    cvtW<<<dim3(64, 4), 256, 0, stream>>>(Wq, Wk, Wv, Wo, wall);

    // z 0..2: A -> Q(dir0), K(dir1), V(dir1); z 3..5: B -> Q(dir1), K(dir0), V(dir0)
    qkv_proj<<<dim3(64, 4, 6), 256, 0, stream>>>(abf, bbf, wall, q0, k1, vt1, q1, k0, vt0);

    attn<<<dim3(32, 4, 8), 256, 0, stream>>>(q0, k0, vt0, q1, k1, vt1, Opart, ML);

    out_proj<<<dim3(64, 4, 2), 256, 0, stream>>>(Opart, ML, wall + 3 * 65536, bo, A, B, out);
}

// Round 12
// 104.092 us; speedup vs baseline: 1.0411x; 1.0411x over previous
//
#include <hip/hip_runtime.h>
#include <hip/hip_bf16.h>
#include <math.h>

#define EMB 256
#define HEADS 4
#define HD 64
#define NTOK 4096

typedef __attribute__((ext_vector_type(8))) short bf16x8;
typedef __attribute__((ext_vector_type(4))) float f32x4;
typedef __attribute__((ext_vector_type(16))) float f32x16;
typedef __attribute__((ext_vector_type(2))) unsigned int uint2v;

#define MFMA16(a, b, c) __builtin_amdgcn_mfma_f32_16x16x32_bf16(a, b, c, 0, 0, 0)
#define MFMA32(a, b, c) __builtin_amdgcn_mfma_f32_32x32x16_bf16(a, b, c, 0, 0, 0)

static __device__ __forceinline__ ushort f2bf(float f) {
    __hip_bfloat16 h = __float2bfloat16(f);
    return *(ushort*)&h;
}
static __device__ __forceinline__ float ex2(float x) { return __builtin_amdgcn_exp2f(x); }
static __device__ __forceinline__ uint pkbf(float lo, float hi) {
    uint r;
    asm("v_cvt_pk_bf16_f32 %0, %1, %2" : "=v"(r) : "v"(lo), "v"(hi));
    return r;
}
static __device__ __forceinline__ float max3f(float a, float b, float c) {
    float r;
    asm("v_max3_f32 %0, %1, %2, %3" : "=v"(r) : "v"(a), "v"(b), "v"(c));
    return r;
}
// cross-half (lane^32) reductions on the VALU pipe via self permlane32_swap
static __device__ __forceinline__ float redmax32(float x) {
    uint xi = __float_as_uint(x);
    uint2v r = __builtin_amdgcn_permlane32_swap(xi, xi, false, false);
    return fmaxf(__uint_as_float(r[0]), __uint_as_float(r[1]));
}
static __device__ __forceinline__ float redsum32(float x) {
    uint xi = __float_as_uint(x);
    uint2v r = __builtin_amdgcn_permlane32_swap(xi, xi, false, false);
    return __uint_as_float(r[0]) + __uint_as_float(r[1]);
}
static __device__ __forceinline__ bf16x8 cvt8(float4 a, float4 b) {
    union { uint u[4]; bf16x8 h; } pk;
    pk.u[0] = pkbf(a.x, a.y);
    pk.u[1] = pkbf(a.z, a.w);
    pk.u[2] = pkbf(b.x, b.y);
    pk.u[3] = pkbf(b.z, b.w);
    return pk.h;
}
static __device__ __forceinline__ float bf2f(ushort u) {
    return __uint_as_float(((uint)u) << 16);
}

// ---------------- all f32 -> bf16 conversions, one launch ----------------
// blocks 0..2047: A,B (1024 each); 2048..2303: Wq,Wk,Wv,Wo (64 each)
__global__ void cvt_all(const float* __restrict__ A, const float* __restrict__ B,
                        const float* __restrict__ Wq, const float* __restrict__ Wk,
                        const float* __restrict__ Wv, const float* __restrict__ Wo,
                        ushort* __restrict__ Ao, ushort* __restrict__ Bo,
                        ushort* __restrict__ Wall) {
    int b = blockIdx.x;
    const float* s;
    ushort* d;
    int chunk;
    if (b < 2048) {
        s = (b >= 1024) ? B : A;
        d = (b >= 1024) ? Bo : Ao;
        chunk = b & 1023;
    } else {
        int wb = b - 2048;
        int wsel = wb >> 6;
        s = (wsel == 0) ? Wq : (wsel == 1) ? Wk : (wsel == 2) ? Wv : Wo;
        d = Wall + (size_t)wsel * 65536;
        chunk = wb & 63;
    }
    int i = (chunk * 256 + threadIdx.x) * 4;
    float4 v = *(const float4*)(s + i);
    ushort4 o;
    o.x = f2bf(v.x); o.y = f2bf(v.y); o.z = f2bf(v.z); o.w = f2bf(v.w);
    *(ushort4*)(d + i) = o;
}

// ---------------- QKV projection (separate kinds; bf16 X input) ----------------
// kind=0: Q [m][256] pre-scaled by log2(e)/8; kind=1: K [m][256]
// kind=2: V transposed per head, token bit-2/3-swapped: Vt[h][d][perm(m)]
// NOTE: keep kinds SEPARATE — fusing the 3 projections in one block blows
// absmax 0.0156->0.082 (R6-R9 controlled experiment).
__global__ __launch_bounds__(256) void qkv_proj(const ushort* __restrict__ Xa,
                                                const ushort* __restrict__ Xb,
                                                const ushort* __restrict__ Wall,
                                                ushort* __restrict__ Q0, ushort* __restrict__ K1, ushort* __restrict__ Vt1,
                                                ushort* __restrict__ Q1, ushort* __restrict__ K0, ushort* __restrict__ Vt0) {
    int w = threadIdx.x >> 6, lane = threadIdx.x & 63;
    int lr = lane & 15, lg = lane >> 4;
    int z = blockIdx.z;
    int kind = (z < 3) ? z : z - 3;
    const ushort* X = (z < 3) ? Xa : Xb;
    ushort* Qo = (z < 3) ? Q0 : Q1;
    ushort* Ko = (z < 3) ? K1 : K0;
    ushort* Vto = (z < 3) ? Vt1 : Vt0;
    const ushort* W = Wall + (size_t)kind * 65536;
    int rbase = blockIdx.x * 64 + w * 16;
    int cbase = blockIdx.y * 64;

    f32x4 acc[4] = {};
#pragma unroll
    for (int kk = 0; kk < 256; kk += 32) {
        bf16x8 a = *(const bf16x8*)(X + (size_t)(rbase + lr) * EMB + kk + lg * 8);
#pragma unroll
        for (int cj = 0; cj < 4; ++cj) {
            bf16x8 b = *(const bf16x8*)(W + (size_t)(cbase + cj * 16 + lr) * EMB + kk + lg * 8);
            acc[cj] = MFMA16(a, b, acc[cj]);
        }
    }
    const float QS = 0.125f * 1.4426950408889634f;  // 1/sqrt(64) * log2(e)
#pragma unroll
    for (int cj = 0; cj < 4; ++cj)
#pragma unroll
        for (int j = 0; j < 4; ++j) {
            int R = rbase + lg * 4 + j;
            int col = cbase + cj * 16 + lr;
            float v = acc[cj][j];
            if (kind == 0) {
                Qo[(size_t)R * EMB + col] = f2bf(v * QS);
            } else if (kind == 1) {
                Ko[(size_t)R * EMB + col] = f2bf(v);
            } else {
                int h = col >> 6, d = col & 63;
                int Rp = (R & ~12) | ((R & 4) << 1) | ((R & 8) >> 1);  // swap bits 2,3
                Vto[(size_t)h * HD * NTOK + (size_t)d * NTOK + Rp] = f2bf(v);
            }
        }
}

// ---------------- flash cross-attention, swapped-QK 32x32, kv-split=4 ----------------
// grid (32,4,8): 1024 blocks. Double-buffered LDS, ONE barrier/tile; next-tile
// global loads issued BEFORE the barrier (ds_write operands latch at issue ->
// WAR-safe), so HBM latency hides under barrier-wait + compute.
// Occupancy is capped by the unified reg file (~128/wave incl AGPR acc) at 4
// waves/SIMD — do NOT trade LDS for occupancy (R9), do NOT force (256,8) (R6).
// Epilogue stores MUST be scalar f2bf: v_cvt_pk_bf16_f32 rounds worse and
// doubles absmax (R11: 0.0156 -> 0.031).
__global__ __launch_bounds__(256, 4) void attn(const ushort* __restrict__ Q0,
                                               const ushort* __restrict__ K0,
                                               const ushort* __restrict__ Vt0,
                                               const ushort* __restrict__ Q1,
                                               const ushort* __restrict__ K1,
                                               const ushort* __restrict__ Vt1,
                                               ushort* __restrict__ Opart,
                                               float* __restrict__ ML) {
    __shared__ ushort lK[2][64 * 64];
    __shared__ ushort lV[2][64 * 64];

    // bijective XCD swizzle over 1024 blocks
    int fb = blockIdx.x + 32 * blockIdx.y + 128 * blockIdx.z;
    int nf = (fb & 7) * 128 + (fb >> 3);
    int qt = nf & 31;
    int head = (nf >> 5) & 3;
    int z = nf >> 7;               // 0..7
    int dir = z >> 2, split = z & 3;
    int kv0 = split * 1024;

    const ushort* Q = dir ? Q1 : Q0;
    const ushort* K = dir ? K1 : K0;
    const ushort* Vt = dir ? Vt1 : Vt0;
    const ushort* Vth = Vt + (size_t)head * HD * NTOK;

    int wq = threadIdx.x >> 6;
    int lane = threadIdx.x & 63;
    int l31 = lane & 31, hi = lane >> 5;

    int qg = qt * 128 + wq * 32 + l31;
    bf16x8 qf[4];
#pragma unroll
    for (int ks = 0; ks < 4; ++ks)
        qf[ks] = *(const bf16x8*)(Q + (size_t)qg * EMB + head * 64 + ks * 16 + hi * 8);

    int srow = threadIdx.x >> 3, sseg = threadIdx.x & 7;
    int ssw = (sseg ^ ((srow >> 2) & 7)) * 8;  // f(r)=(r>>2)&7; f(r+32)==f(r)

    // prologue: prefetch tile 0
    uint4 rk0 = *(const uint4*)(K + (size_t)(kv0 + srow) * EMB + head * 64 + sseg * 8);
    uint4 rk1 = *(const uint4*)(K + (size_t)(kv0 + srow + 32) * EMB + head * 64 + sseg * 8);
    uint4 rv0 = *(const uint4*)(Vth + (size_t)srow * NTOK + kv0 + sseg * 8);
    uint4 rv1 = *(const uint4*)(Vth + (size_t)(srow + 32) * NTOK + kv0 + sseg * 8);

    float m = -1e30f, ls = 0.0f;
    f32x16 oacc0 = {};
    f32x16 oacc1 = {};
    int sw = (l31 >> 2) & 7;  // read-side swizzle key (rows l31 and 32+l31 share it)

    for (int t = 0; t < 16; ++t) {
        int cur = t & 1;
        ushort* lk = &lK[cur][0];
        ushort* lv = &lV[cur][0];
        *(uint4*)(&lk[srow * 64 + ssw]) = rk0;
        *(uint4*)(&lk[(srow + 32) * 64 + ssw]) = rk1;
        *(uint4*)(&lv[srow * 64 + ssw]) = rv0;
        *(uint4*)(&lv[(srow + 32) * 64 + ssw]) = rv1;

        // issue next tile's loads BEFORE the barrier: ds_write has latched its
        // operands, and the loads have no LDS dependency — latency overlaps
        // the barrier wait and this tile's compute.
        if (t < 15) {
            int nkv = kv0 + (t + 1) * 64;
            rk0 = *(const uint4*)(K + (size_t)(nkv + srow) * EMB + head * 64 + sseg * 8);
            rk1 = *(const uint4*)(K + (size_t)(nkv + srow + 32) * EMB + head * 64 + sseg * 8);
            rv0 = *(const uint4*)(Vth + (size_t)srow * NTOK + nkv + sseg * 8);
            rv1 = *(const uint4*)(Vth + (size_t)(srow + 32) * NTOK + nkv + sseg * 8);
        }
        __syncthreads();  // sole barrier: buffer ready for all

        // QK^T swapped: lane holds 32 scores for q-row l31
        f32x16 sA = {}, sB = {};
        __builtin_amdgcn_s_setprio(1);
#pragma unroll
        for (int ks = 0; ks < 4; ++ks) {
            bf16x8 ka = *(const bf16x8*)(&lk[l31 * 64 + ((ks * 2 + hi) ^ sw) * 8]);
            bf16x8 kb = *(const bf16x8*)(&lk[(32 + l31) * 64 + ((ks * 2 + hi) ^ sw) * 8]);
            sA = MFMA32(ka, qf[ks], sA);
            sB = MFMA32(kb, qf[ks], sB);
        }
        __builtin_amdgcn_s_setprio(0);

        // tile max via v_max3 tree
        float t0 = max3f(sA[0], sA[1], sA[2]);
        float t1 = max3f(sA[3], sA[4], sA[5]);
        float t2 = max3f(sA[6], sA[7], sA[8]);
        float t3 = max3f(sA[9], sA[10], sA[11]);
        float t4 = max3f(sA[12], sA[13], sA[14]);
        float t5 = max3f(sB[0], sB[1], sB[2]);
        float t6 = max3f(sB[3], sB[4], sB[5]);
        float t7 = max3f(sB[6], sB[7], sB[8]);
        float t8 = max3f(sB[9], sB[10], sB[11]);
        float t9 = max3f(sB[12], sB[13], sB[14]);
        float ta = fmaxf(sA[15], sB[15]);
        float u0 = max3f(t0, t1, t2);
        float u1 = max3f(t3, t4, t5);
        float u2 = max3f(t6, t7, t8);
        float u3 = fmaxf(t9, ta);
        float tmax = redmax32(fmaxf(max3f(u0, u1, u2), u3));

        // defer-max (THR=8)
        if (__any(tmax > m + 8.0f)) {
            float mn = fmaxf(m, tmax);
            float sc = ex2(m - mn);
            m = mn;
            ls *= sc;
#pragma unroll
            for (int r = 0; r < 16; ++r) { oacc0[r] *= sc; oacc1[r] *= sc; }
        }

#pragma unroll
        for (int r = 0; r < 16; ++r) sA[r] = ex2(sA[r] - m);
#pragma unroll
        for (int r = 0; r < 16; ++r) sB[r] = ex2(sB[r] - m);

        // pairwise-tree row sum
        float s1[16];
#pragma unroll
        for (int i = 0; i < 8; ++i) s1[i] = sA[2 * i] + sA[2 * i + 1];
#pragma unroll
        for (int i = 0; i < 8; ++i) s1[8 + i] = sB[2 * i] + sB[2 * i + 1];
#pragma unroll
        for (int w2 = 8; w2 >= 1; w2 >>= 1)
#pragma unroll
            for (int i = 0; i < 8; ++i)
                if (i < w2) s1[i] = s1[2 * i] + s1[2 * i + 1];
        ls += redsum32(s1[0]);

        // P -> bf16 fragments (lane-local; V pre-permuted to match)
        bf16x8 pa[4];
#pragma unroll
        for (int ks = 0; ks < 4; ++ks) {
            union { uint u[4]; bf16x8 h; } pk;
#pragma unroll
            for (int j = 0; j < 4; ++j) {
                float lo = (ks < 2) ? sA[(ks & 1) * 8 + 2 * j] : sB[(ks & 1) * 8 + 2 * j];
                float hv = (ks < 2) ? sA[(ks & 1) * 8 + 2 * j + 1] : sB[(ks & 1) * 8 + 2 * j + 1];
                pk.u[j] = pkbf(lo, hv);
            }
            pa[ks] = pk.h;
        }

        __builtin_amdgcn_s_setprio(1);
#pragma unroll
        for (int ks = 0; ks < 4; ++ks) {
            bf16x8 va = *(const bf16x8*)(&lv[l31 * 64 + ((ks * 2 + hi) ^ sw) * 8]);
            bf16x8 vb = *(const bf16x8*)(&lv[(32 + l31) * 64 + ((ks * 2 + hi) ^ sw) * 8]);
            oacc0 = MFMA32(va, pa[ks], oacc0);
            oacc1 = MFMA32(vb, pa[ks], oacc1);
        }
        __builtin_amdgcn_s_setprio(0);
    }

    // epilogue: unnormalized bf16 partials + (m, l) — scalar f2bf (RNE)
    ushort* Ob = Opart + ((size_t)z * 4096 + qg) * 256 + head * 64;
#pragma unroll
    for (int r = 0; r < 16; ++r) {
        int crow = (r & 3) + 8 * (r >> 2) + 4 * hi;
        Ob[crow] = f2bf(oacc0[r]);
        Ob[32 + crow] = f2bf(oacc1[r]);
    }
    if (hi == 0) {
        float2* mlp = (float2*)ML;
        mlp[((size_t)z * 4 + head) * 4096 + qg] = make_float2(m, ls);
    }
}

// ---------------- streaming 4-way merge: bf16 Opart -> normalized ctx (bf16) ----------------
__global__ __launch_bounds__(256) void merge(const ushort* __restrict__ Opart,
                                             const float* __restrict__ ML,
                                             ushort* __restrict__ C0,
                                             ushort* __restrict__ C1) {
    int idx = blockIdx.x * 256 + threadIdx.x;  // 0..262143: dir(1) q(12) head(2) dblk(3)
    int dblk = idx & 7;
    int head = (idx >> 3) & 3;
    int q = (idx >> 5) & 4095;
    int dir = idx >> 17;

    const float2* mlp = (const float2*)ML;
    float2 ml[4];
    float M = -1e30f;
#pragma unroll
    for (int s = 0; s < 4; ++s) {
        ml[s] = mlp[((size_t)(dir * 4 + s) * 4 + head) * 4096 + q];
        M = fmaxf(M, ml[s].x);
    }
    float denom = 0.0f, a[4];
#pragma unroll
    for (int s = 0; s < 4; ++s) { a[s] = ex2(ml[s].x - M); denom += a[s] * ml[s].y; }
    float inv = 1.0f / denom;

    float accv[8] = {};
#pragma unroll
    for (int s = 0; s < 4; ++s) {
        float ws = a[s] * inv;
        bf16x8 x = *(const bf16x8*)(Opart + ((size_t)(dir * 4 + s) * 4096 + q) * 256 + head * 64 + dblk * 8);
#pragma unroll
        for (int u = 0; u < 8; ++u) accv[u] += ws * bf2f((ushort)x[u]);
    }
    ushort* C = (dir ? C1 : C0) + (size_t)q * 256 + head * 64 + dblk * 8;
    ushort o[8];
#pragma unroll
    for (int u = 0; u < 8; ++u) o[u] = f2bf(accv[u]);
    *(uint4*)C = *(uint4*)o;
}

// ---------------- output projection: out = Ctx @ Wo^T + bo + X ----------------
__global__ __launch_bounds__(256) void out_proj(const ushort* __restrict__ C0,
                                                const ushort* __restrict__ C1,
                                                const ushort* __restrict__ Wo,
                                                const float* __restrict__ bo,
                                                const float* __restrict__ A,
                                                const float* __restrict__ B,
                                                float* __restrict__ out) {
    int dir = blockIdx.z;
    const ushort* Ctx = dir ? C1 : C0;
    const float* X = dir ? B : A;
    float* o = out + (size_t)dir * NTOK * EMB;

    int w = threadIdx.x >> 6, lane = threadIdx.x & 63;
    int lr = lane & 15, lg = lane >> 4;
    int rbase = blockIdx.x * 64 + w * 16;
    int cbase = blockIdx.y * 64;

    f32x4 acc[4] = {};
#pragma unroll
    for (int kk = 0; kk < 256; kk += 32) {
        bf16x8 a = *(const bf16x8*)(Ctx + (size_t)(rbase + lr) * EMB + kk + lg * 8);
#pragma unroll
        for (int cj = 0; cj < 4; ++cj) {
            bf16x8 b = *(const bf16x8*)(Wo + (size_t)(cbase + cj * 16 + lr) * EMB + kk + lg * 8);
            acc[cj] = MFMA16(a, b, acc[cj]);
        }
    }
#pragma unroll
    for (int cj = 0; cj < 4; ++cj)
#pragma unroll
        for (int j = 0; j < 4; ++j) {
            int R = rbase + lg * 4 + j;
            int col = cbase + cj * 16 + lr;
            o[(size_t)R * EMB + col] = acc[cj][j] + bo[col] + X[(size_t)R * EMB + col];
        }
}

extern "C" void kernel_launch(void* const* d_in, const int* in_sizes, int n_in,
                              void* d_out, int out_size, void* d_ws, size_t ws_size,
                              hipStream_t stream) {
    const float* A  = (const float*)d_in[0];
    const float* B  = (const float*)d_in[1];
    const float* Wq = (const float*)d_in[2];
    const float* Wk = (const float*)d_in[3];
    const float* Wv = (const float*)d_in[4];
    const float* Wo = (const float*)d_in[5];
    const float* bo = (const float*)d_in[6];
    float* out = (float*)d_out;

    ushort* ws = (ushort*)d_ws;
    const size_t TE = (size_t)NTOK * EMB;  // 1048576 elements
    ushort* wall = ws;                 // 4 * 65536
    ushort* abf = wall + 4 * 65536;
    ushort* bbf = abf + TE;
    ushort* q0  = bbf + TE;
    ushort* q1  = q0 + TE;
    ushort* k0  = q1 + TE;
    ushort* k1  = k0 + TE;
    ushort* vt0 = k1 + TE;
    ushort* vt1 = vt0 + TE;
    ushort* c0  = vt1 + TE;
    ushort* c1  = c0 + TE;
    ushort* Opart = c1 + TE;                               // 8 x 4096 x 256 bf16 = 16 MB
    float* ML = (float*)(Opart + (size_t)8 * 4096 * 256);  // 8 x 4 x 4096 float2 = 1 MB

    cvt_all<<<dim3(2304), 256, 0, stream>>>(A, B, Wq, Wk, Wv, Wo, abf, bbf, wall);

    // z 0..2: A -> Q(dir0), K(dir1), V(dir1); z 3..5: B -> Q(dir1), K(dir0), V(dir0)
    qkv_proj<<<dim3(64, 4, 6), 256, 0, stream>>>(abf, bbf, wall, q0, k1, vt1, q1, k0, vt0);

    attn<<<dim3(32, 4, 8), 256, 0, stream>>>(q0, k0, vt0, q1, k1, vt1, Opart, ML);

    merge<<<dim3(1024), 256, 0, stream>>>(Opart, ML, c0, c1);

    out_proj<<<dim3(64, 4, 2), 256, 0, stream>>>(c0, c1, wall + 3 * 65536, bo, A, B, out);
}

// Round 13
// 100.759 us; speedup vs baseline: 1.0755x; 1.0331x over previous
//
#include <hip/hip_runtime.h>
#include <hip/hip_bf16.h>
#include <math.h>

#define EMB 256
#define HEADS 4
#define HD 64
#define NTOK 4096

typedef __attribute__((ext_vector_type(8))) short bf16x8;
typedef __attribute__((ext_vector_type(4))) float f32x4;
typedef __attribute__((ext_vector_type(16))) float f32x16;
typedef __attribute__((ext_vector_type(2))) unsigned int uint2v;

#define MFMA16(a, b, c) __builtin_amdgcn_mfma_f32_16x16x32_bf16(a, b, c, 0, 0, 0)
#define MFMA32(a, b, c) __builtin_amdgcn_mfma_f32_32x32x16_bf16(a, b, c, 0, 0, 0)

static __device__ __forceinline__ ushort f2bf(float f) {
    __hip_bfloat16 h = __float2bfloat16(f);
    return *(ushort*)&h;
}
static __device__ __forceinline__ float ex2(float x) { return __builtin_amdgcn_exp2f(x); }
// NOTE: v_cvt_pk_bf16_f32 does NOT round like __float2bfloat16 (RNE).
// Use it ONLY for P in [0,1] fragments (errors wash out in the normalized
// sum). Using it on X (R6-R8) gave absmax 0.082; on O-partials (R11) 0.031.
static __device__ __forceinline__ uint pkbf(float lo, float hi) {
    uint r;
    asm("v_cvt_pk_bf16_f32 %0, %1, %2" : "=v"(r) : "v"(lo), "v"(hi));
    return r;
}
static __device__ __forceinline__ float max3f(float a, float b, float c) {
    float r;
    asm("v_max3_f32 %0, %1, %2, %3" : "=v"(r) : "v"(a), "v"(b), "v"(c));
    return r;
}
// cross-half (lane^32) reductions on the VALU pipe via self permlane32_swap
static __device__ __forceinline__ float redmax32(float x) {
    uint xi = __float_as_uint(x);
    uint2v r = __builtin_amdgcn_permlane32_swap(xi, xi, false, false);
    return fmaxf(__uint_as_float(r[0]), __uint_as_float(r[1]));
}
static __device__ __forceinline__ float redsum32(float x) {
    uint xi = __float_as_uint(x);
    uint2v r = __builtin_amdgcn_permlane32_swap(xi, xi, false, false);
    return __uint_as_float(r[0]) + __uint_as_float(r[1]);
}
static __device__ __forceinline__ float bf2f(ushort u) {
    return __uint_as_float(((uint)u) << 16);
}

// ---------------- all f32 -> bf16 conversions, one launch (RNE via f2bf) ----------------
// blocks 0..2047: A,B (1024 each); 2048..2303: Wq,Wk,Wv,Wo (64 each)
__global__ void cvt_all(const float* __restrict__ A, const float* __restrict__ B,
                        const float* __restrict__ Wq, const float* __restrict__ Wk,
                        const float* __restrict__ Wv, const float* __restrict__ Wo,
                        ushort* __restrict__ Ao, ushort* __restrict__ Bo,
                        ushort* __restrict__ Wall) {
    int b = blockIdx.x;
    const float* s;
    ushort* d;
    int chunk;
    if (b < 2048) {
        s = (b >= 1024) ? B : A;
        d = (b >= 1024) ? Bo : Ao;
        chunk = b & 1023;
    } else {
        int wb = b - 2048;
        int wsel = wb >> 6;
        s = (wsel == 0) ? Wq : (wsel == 1) ? Wk : (wsel == 2) ? Wv : Wo;
        d = Wall + (size_t)wsel * 65536;
        chunk = wb & 63;
    }
    int i = (chunk * 256 + threadIdx.x) * 4;
    float4 v = *(const float4*)(s + i);
    ushort4 o;
    o.x = f2bf(v.x); o.y = f2bf(v.y); o.z = f2bf(v.z); o.w = f2bf(v.w);
    *(ushort4*)(d + i) = o;
}

// ---------------- fused QKV projection (bf16 X input, one X read per tile) ----------------
// One block computes Q, K, V for a 64x64 tile. Per-accumulator MFMA order is
// identical to the separate-kind version, so numerics match (absmax culprit
// was pkbf-converted X, not fusion — R6-R9 forensics).
// Q pre-scaled by log2(e)/8; V transposed per head, token bit-2/3-swapped.
__global__ __launch_bounds__(256) void qkv_proj(const ushort* __restrict__ Xa,
                                                const ushort* __restrict__ Xb,
                                                const ushort* __restrict__ Wall,
                                                ushort* __restrict__ Q0, ushort* __restrict__ K1, ushort* __restrict__ Vt1,
                                                ushort* __restrict__ Q1, ushort* __restrict__ K0, ushort* __restrict__ Vt0) {
    int w = threadIdx.x >> 6, lane = threadIdx.x & 63;
    int lr = lane & 15, lg = lane >> 4;
    int z = blockIdx.z;  // source: 0=A, 1=B
    const ushort* X = z ? Xb : Xa;
    ushort* Qo = z ? Q1 : Q0;
    ushort* Ko = z ? K0 : K1;   // A feeds K of dir1; B feeds K of dir0
    ushort* Vto = z ? Vt0 : Vt1;
    int rbase = blockIdx.x * 64 + w * 16;
    int cbase = blockIdx.y * 64;

    f32x4 acc[3][4] = {};
#pragma unroll
    for (int kk = 0; kk < 256; kk += 32) {
        bf16x8 a = *(const bf16x8*)(X + (size_t)(rbase + lr) * EMB + kk + lg * 8);
#pragma unroll
        for (int kind = 0; kind < 3; ++kind) {
            const ushort* W = Wall + (size_t)kind * 65536;
#pragma unroll
            for (int cj = 0; cj < 4; ++cj) {
                bf16x8 b = *(const bf16x8*)(W + (size_t)(cbase + cj * 16 + lr) * EMB + kk + lg * 8);
                acc[kind][cj] = MFMA16(a, b, acc[kind][cj]);
            }
        }
    }
    const float QS = 0.125f * 1.4426950408889634f;  // 1/sqrt(64) * log2(e)
#pragma unroll
    for (int cj = 0; cj < 4; ++cj)
#pragma unroll
        for (int j = 0; j < 4; ++j) {
            int R = rbase + lg * 4 + j;
            int col = cbase + cj * 16 + lr;
            Qo[(size_t)R * EMB + col] = f2bf(acc[0][cj][j] * QS);
            Ko[(size_t)R * EMB + col] = f2bf(acc[1][cj][j]);
            int h = col >> 6, d = col & 63;
            int Rp = (R & ~12) | ((R & 4) << 1) | ((R & 8) >> 1);  // swap bits 2,3
            Vto[(size_t)h * HD * NTOK + (size_t)d * NTOK + Rp] = f2bf(acc[2][cj][j]);
        }
}

// ---------------- flash cross-attention, swapped-QK 32x32, kv-split=4 ----------------
// grid (32,4,8): 1024 blocks. Double-buffered LDS, ONE barrier/tile; next-tile
// global loads issued BEFORE the barrier (WAR-safe: ds_write operands latch).
// Occupancy is capped by the unified reg file at 4 waves/SIMD — do NOT trade
// LDS for occupancy (R9), do NOT force (256,8) (R6).
// Epilogue stores MUST be scalar f2bf (RNE); pkbf here doubles absmax (R11).
__global__ __launch_bounds__(256, 4) void attn(const ushort* __restrict__ Q0,
                                               const ushort* __restrict__ K0,
                                               const ushort* __restrict__ Vt0,
                                               const ushort* __restrict__ Q1,
                                               const ushort* __restrict__ K1,
                                               const ushort* __restrict__ Vt1,
                                               ushort* __restrict__ Opart,
                                               float* __restrict__ ML) {
    __shared__ ushort lK[2][64 * 64];
    __shared__ ushort lV[2][64 * 64];

    // bijective XCD swizzle over 1024 blocks
    int fb = blockIdx.x + 32 * blockIdx.y + 128 * blockIdx.z;
    int nf = (fb & 7) * 128 + (fb >> 3);
    int qt = nf & 31;
    int head = (nf >> 5) & 3;
    int z = nf >> 7;               // 0..7
    int dir = z >> 2, split = z & 3;
    int kv0 = split * 1024;

    const ushort* Q = dir ? Q1 : Q0;
    const ushort* K = dir ? K1 : K0;
    const ushort* Vt = dir ? Vt1 : Vt0;
    const ushort* Vth = Vt + (size_t)head * HD * NTOK;

    int wq = threadIdx.x >> 6;
    int lane = threadIdx.x & 63;
    int l31 = lane & 31, hi = lane >> 5;

    int qg = qt * 128 + wq * 32 + l31;
    bf16x8 qf[4];
#pragma unroll
    for (int ks = 0; ks < 4; ++ks)
        qf[ks] = *(const bf16x8*)(Q + (size_t)qg * EMB + head * 64 + ks * 16 + hi * 8);

    int srow = threadIdx.x >> 3, sseg = threadIdx.x & 7;
    int ssw = (sseg ^ ((srow >> 2) & 7)) * 8;  // f(r)=(r>>2)&7; f(r+32)==f(r)

    // prologue: prefetch tile 0
    uint4 rk0 = *(const uint4*)(K + (size_t)(kv0 + srow) * EMB + head * 64 + sseg * 8);
    uint4 rk1 = *(const uint4*)(K + (size_t)(kv0 + srow + 32) * EMB + head * 64 + sseg * 8);
    uint4 rv0 = *(const uint4*)(Vth + (size_t)srow * NTOK + kv0 + sseg * 8);
    uint4 rv1 = *(const uint4*)(Vth + (size_t)(srow + 32) * NTOK + kv0 + sseg * 8);

    float m = -1e30f, ls = 0.0f;
    f32x16 oacc0 = {};
    f32x16 oacc1 = {};
    int sw = (l31 >> 2) & 7;  // read-side swizzle key (rows l31 and 32+l31 share it)

    for (int t = 0; t < 16; ++t) {
        int cur = t & 1;
        ushort* lk = &lK[cur][0];
        ushort* lv = &lV[cur][0];
        *(uint4*)(&lk[srow * 64 + ssw]) = rk0;
        *(uint4*)(&lk[(srow + 32) * 64 + ssw]) = rk1;
        *(uint4*)(&lv[srow * 64 + ssw]) = rv0;
        *(uint4*)(&lv[(srow + 32) * 64 + ssw]) = rv1;

        if (t < 15) {
            int nkv = kv0 + (t + 1) * 64;
            rk0 = *(const uint4*)(K + (size_t)(nkv + srow) * EMB + head * 64 + sseg * 8);
            rk1 = *(const uint4*)(K + (size_t)(nkv + srow + 32) * EMB + head * 64 + sseg * 8);
            rv0 = *(const uint4*)(Vth + (size_t)srow * NTOK + nkv + sseg * 8);
            rv1 = *(const uint4*)(Vth + (size_t)(srow + 32) * NTOK + nkv + sseg * 8);
        }
        __syncthreads();  // sole barrier: buffer ready for all

        // QK^T swapped: lane holds 32 scores for q-row l31
        f32x16 sA = {}, sB = {};
        __builtin_amdgcn_s_setprio(1);
#pragma unroll
        for (int ks = 0; ks < 4; ++ks) {
            bf16x8 ka = *(const bf16x8*)(&lk[l31 * 64 + ((ks * 2 + hi) ^ sw) * 8]);
            bf16x8 kb = *(const bf16x8*)(&lk[(32 + l31) * 64 + ((ks * 2 + hi) ^ sw) * 8]);
            sA = MFMA32(ka, qf[ks], sA);
            sB = MFMA32(kb, qf[ks], sB);
        }
        __builtin_amdgcn_s_setprio(0);

        // tile max via v_max3 tree
        float t0 = max3f(sA[0], sA[1], sA[2]);
        float t1 = max3f(sA[3], sA[4], sA[5]);
        float t2 = max3f(sA[6], sA[7], sA[8]);
        float t3 = max3f(sA[9], sA[10], sA[11]);
        float t4 = max3f(sA[12], sA[13], sA[14]);
        float t5 = max3f(sB[0], sB[1], sB[2]);
        float t6 = max3f(sB[3], sB[4], sB[5]);
        float t7 = max3f(sB[6], sB[7], sB[8]);
        float t8 = max3f(sB[9], sB[10], sB[11]);
        float t9 = max3f(sB[12], sB[13], sB[14]);
        float ta = fmaxf(sA[15], sB[15]);
        float u0 = max3f(t0, t1, t2);
        float u1 = max3f(t3, t4, t5);
        float u2 = max3f(t6, t7, t8);
        float u3 = fmaxf(t9, ta);
        float tmax = redmax32(fmaxf(max3f(u0, u1, u2), u3));

        // defer-max (THR=8)
        if (__any(tmax > m + 8.0f)) {
            float mn = fmaxf(m, tmax);
            float sc = ex2(m - mn);
            m = mn;
            ls *= sc;
#pragma unroll
            for (int r = 0; r < 16; ++r) { oacc0[r] *= sc; oacc1[r] *= sc; }
        }

#pragma unroll
        for (int r = 0; r < 16; ++r) sA[r] = ex2(sA[r] - m);
#pragma unroll
        for (int r = 0; r < 16; ++r) sB[r] = ex2(sB[r] - m);

        // pairwise-tree row sum
        float s1[16];
#pragma unroll
        for (int i = 0; i < 8; ++i) s1[i] = sA[2 * i] + sA[2 * i + 1];
#pragma unroll
        for (int i = 0; i < 8; ++i) s1[8 + i] = sB[2 * i] + sB[2 * i + 1];
#pragma unroll
        for (int w2 = 8; w2 >= 1; w2 >>= 1)
#pragma unroll
            for (int i = 0; i < 8; ++i)
                if (i < w2) s1[i] = s1[2 * i] + s1[2 * i + 1];
        ls += redsum32(s1[0]);

        // P -> bf16 fragments via pkbf (safe here: P in [0,1], errors wash out)
        bf16x8 pa[4];
#pragma unroll
        for (int ks = 0; ks < 4; ++ks) {
            union { uint u[4]; bf16x8 h; } pk;
#pragma unroll
            for (int j = 0; j < 4; ++j) {
                float lo = (ks < 2) ? sA[(ks & 1) * 8 + 2 * j] : sB[(ks & 1) * 8 + 2 * j];
                float hv = (ks < 2) ? sA[(ks & 1) * 8 + 2 * j + 1] : sB[(ks & 1) * 8 + 2 * j + 1];
                pk.u[j] = pkbf(lo, hv);
            }
            pa[ks] = pk.h;
        }

        __builtin_amdgcn_s_setprio(1);
#pragma unroll
        for (int ks = 0; ks < 4; ++ks) {
            bf16x8 va = *(const bf16x8*)(&lv[l31 * 64 + ((ks * 2 + hi) ^ sw) * 8]);
            bf16x8 vb = *(const bf16x8*)(&lv[(32 + l31) * 64 + ((ks * 2 + hi) ^ sw) * 8]);
            oacc0 = MFMA32(va, pa[ks], oacc0);
            oacc1 = MFMA32(vb, pa[ks], oacc1);
        }
        __builtin_amdgcn_s_setprio(0);
    }

    // epilogue: unnormalized bf16 partials + (m, l) — scalar f2bf (RNE)
    ushort* Ob = Opart + ((size_t)z * 4096 + qg) * 256 + head * 64;
#pragma unroll
    for (int r = 0; r < 16; ++r) {
        int crow = (r & 3) + 8 * (r >> 2) + 4 * hi;
        Ob[crow] = f2bf(oacc0[r]);
        Ob[32 + crow] = f2bf(oacc1[r]);
    }
    if (hi == 0) {
        float2* mlp = (float2*)ML;
        mlp[((size_t)z * 4 + head) * 4096 + qg] = make_float2(m, ls);
    }
}

// ---------------- streaming 4-way merge: bf16 Opart -> normalized ctx (bf16) ----------------
__global__ __launch_bounds__(256) void merge(const ushort* __restrict__ Opart,
                                             const float* __restrict__ ML,
                                             ushort* __restrict__ C0,
                                             ushort* __restrict__ C1) {
    int idx = blockIdx.x * 256 + threadIdx.x;  // 0..262143: dir(1) q(12) head(2) dblk(3)
    int dblk = idx & 7;
    int head = (idx >> 3) & 3;
    int q = (idx >> 5) & 4095;
    int dir = idx >> 17;

    const float2* mlp = (const float2*)ML;
    float2 ml[4];
    float M = -1e30f;
#pragma unroll
    for (int s = 0; s < 4; ++s) {
        ml[s] = mlp[((size_t)(dir * 4 + s) * 4 + head) * 4096 + q];
        M = fmaxf(M, ml[s].x);
    }
    float denom = 0.0f, a[4];
#pragma unroll
    for (int s = 0; s < 4; ++s) { a[s] = ex2(ml[s].x - M); denom += a[s] * ml[s].y; }
    float inv = 1.0f / denom;

    float accv[8] = {};
#pragma unroll
    for (int s = 0; s < 4; ++s) {
        float ws = a[s] * inv;
        bf16x8 x = *(const bf16x8*)(Opart + ((size_t)(dir * 4 + s) * 4096 + q) * 256 + head * 64 + dblk * 8);
#pragma unroll
        for (int u = 0; u < 8; ++u) accv[u] += ws * bf2f((ushort)x[u]);
    }
    ushort* C = (dir ? C1 : C0) + (size_t)q * 256 + head * 64 + dblk * 8;
    ushort o[8];
#pragma unroll
    for (int u = 0; u < 8; ++u) o[u] = f2bf(accv[u]);
    *(uint4*)C = *(uint4*)o;
}

// ---------------- output projection: out = Ctx @ Wo^T + bo + X ----------------
__global__ __launch_bounds__(256) void out_proj(const ushort* __restrict__ C0,
                                                const ushort* __restrict__ C1,
                                                const ushort* __restrict__ Wo,
                                                const float* __restrict__ bo,
                                                const float* __restrict__ A,
                                                const float* __restrict__ B,
                                                float* __restrict__ out) {
    int dir = blockIdx.z;
    const ushort* Ctx = dir ? C1 : C0;
    const float* X = dir ? B : A;
    float* o = out + (size_t)dir * NTOK * EMB;

    int w = threadIdx.x >> 6, lane = threadIdx.x & 63;
    int lr = lane & 15, lg = lane >> 4;
    int rbase = blockIdx.x * 64 + w * 16;
    int cbase = blockIdx.y * 64;

    f32x4 acc[4] = {};
#pragma unroll
    for (int kk = 0; kk < 256; kk += 32) {
        bf16x8 a = *(const bf16x8*)(Ctx + (size_t)(rbase + lr) * EMB + kk + lg * 8);
#pragma unroll
        for (int cj = 0; cj < 4; ++cj) {
            bf16x8 b = *(const bf16x8*)(Wo + (size_t)(cbase + cj * 16 + lr) * EMB + kk + lg * 8);
            acc[cj] = MFMA16(a, b, acc[cj]);
        }
    }
#pragma unroll
    for (int cj = 0; cj < 4; ++cj)
#pragma unroll
        for (int j = 0; j < 4; ++j) {
            int R = rbase + lg * 4 + j;
            int col = cbase + cj * 16 + lr;
            o[(size_t)R * EMB + col] = acc[cj][j] + bo[col] + X[(size_t)R * EMB + col];
        }
}

extern "C" void kernel_launch(void* const* d_in, const int* in_sizes, int n_in,
                              void* d_out, int out_size, void* d_ws, size_t ws_size,
                              hipStream_t stream) {
    const float* A  = (const float*)d_in[0];
    const float* B  = (const float*)d_in[1];
    const float* Wq = (const float*)d_in[2];
    const float* Wk = (const float*)d_in[3];
    const float* Wv = (const float*)d_in[4];
    const float* Wo = (const float*)d_in[5];
    const float* bo = (const float*)d_in[6];
    float* out = (float*)d_out;

    ushort* ws = (ushort*)d_ws;
    const size_t TE = (size_t)NTOK * EMB;  // 1048576 elements
    ushort* wall = ws;                 // 4 * 65536
    ushort* abf = wall + 4 * 65536;
    ushort* bbf = abf + TE;
    ushort* q0  = bbf + TE;
    ushort* q1  = q0 + TE;
    ushort* k0  = q1 + TE;
    ushort* k1  = k0 + TE;
    ushort* vt0 = k1 + TE;
    ushort* vt1 = vt0 + TE;
    ushort* c0  = vt1 + TE;
    ushort* c1  = c0 + TE;
    ushort* Opart = c1 + TE;                               // 8 x 4096 x 256 bf16 = 16 MB
    float* ML = (float*)(Opart + (size_t)8 * 4096 * 256);  // 8 x 4 x 4096 float2 = 1 MB

    cvt_all<<<dim3(2304), 256, 0, stream>>>(A, B, Wq, Wk, Wv, Wo, abf, bbf, wall);

    // z=0: A -> Q(dir0), K(dir1), V(dir1);  z=1: B -> Q(dir1), K(dir0), V(dir0)
    qkv_proj<<<dim3(64, 4, 2), 256, 0, stream>>>(abf, bbf, wall, q0, k1, vt1, q1, k0, vt0);

    attn<<<dim3(32, 4, 8), 256, 0, stream>>>(q0, k0, vt0, q1, k1, vt1, Opart, ML);

    merge<<<dim3(1024), 256, 0, stream>>>(Opart, ML, c0, c1);

    out_proj<<<dim3(64, 4, 2), 256, 0, stream>>>(c0, c1, wall + 3 * 65536, bo, A, B, out);
}